// Round 5
// baseline (480.827 us; speedup 1.0000x reference)
//
#include <hip/hip_runtime.h>
#include <hip/hip_fp16.h>

constexpr int HID = 128;
constexpr int DH  = 64;

typedef _Float16 f16x2 __attribute__((ext_vector_type(2)));
typedef _Float16 fh8   __attribute__((ext_vector_type(8)));   // 4 VGPRs, MFMA A/B frag
typedef float    f32x4v __attribute__((ext_vector_type(4)));  // MFMA C/D frag

__device__ __forceinline__ fh8 relu8(fh8 x) {
  fh8 z = {0, 0, 0, 0, 0, 0, 0, 0};
#if __has_builtin(__builtin_elementwise_max)
  return __builtin_elementwise_max(x, z);
#else
  fh8 r;
#pragma unroll
  for (int i = 0; i < 8; i++) r[i] = x[i] > z[i] ? x[i] : z[i];
  return r;
#endif
}

// ---------------- uv precompute: u = feat @ W1_top, v = feat @ W1_bot + b1 ----------------
// concatenated tables: u_cat[n*256 + roff + j], roff = 0 (pca) / 128 (pimg)
template<int F, int NB>
__launch_bounds__(256)
__global__ void uv_kernel(const float* __restrict__ feat, const float* __restrict__ w1,
                          const float* __restrict__ b1,
                          _Float16* __restrict__ u_cat, _Float16* __restrict__ v_cat,
                          int roff, int N) {
  __shared__ float sfeat[NB][F + 1];
  int nb = blockIdx.x * NB;
  for (int i = threadIdx.x; i < NB * F; i += 256) {
    int n = i / F, k = i - n * F;
    int gn = nb + n;
    sfeat[n][k] = (gn < N) ? feat[(size_t)gn * F + k] : 0.f;
  }
  __syncthreads();
  int j = threadIdx.x & 127;
  int g = threadIdx.x >> 7;           // 0..1
  constexpr int NPT = NB / 2;
  float ua[NPT], va[NPT];
#pragma unroll
  for (int i = 0; i < NPT; i++) { ua[i] = 0.f; va[i] = 0.f; }
  for (int k = 0; k < F; k++) {
    float wu = w1[k * HID + j];
    float wv = w1[(F + k) * HID + j];
#pragma unroll
    for (int i = 0; i < NPT; i++) {
      float f = sfeat[g * NPT + i][k];
      ua[i] = fmaf(f, wu, ua[i]);
      va[i] = fmaf(f, wv, va[i]);
    }
  }
  float b1v = b1[j];
#pragma unroll
  for (int i = 0; i < NPT; i++) {
    int gn = nb + g * NPT + i;
    if (gn < N) {
      u_cat[(size_t)gn * 256 + roff + j] = (_Float16)ua[i];
      v_cat[(size_t)gn * 256 + roff + j] = (_Float16)(va[i] + b1v);
    }
  }
}

// ---------------- h -> fp16 copy ----------------
__global__ void h16_kernel(const float* __restrict__ h, _Float16* __restrict__ h16, int total) {
  int i = (blockIdx.x * 256 + threadIdx.x) * 4;
  if (i + 3 < total) {
    float4 v = *(const float4*)(h + i);
    h16[i] = (_Float16)v.x; h16[i + 1] = (_Float16)v.y;
    h16[i + 2] = (_Float16)v.z; h16[i + 3] = (_Float16)v.w;
  } else {
    for (int q = 0; q < 4; q++) if (i + q < total) h16[i + q] = (_Float16)h[i + q];
  }
}

// ---------------- CSR build ----------------
__global__ void count_kernel(const int* __restrict__ dst, int* __restrict__ counts, int E) {
  int e = blockIdx.x * 256 + threadIdx.x;
  if (e < E) atomicAdd(&counts[dst[e]], 1);
}

__launch_bounds__(256)
__global__ void scan1_kernel(const int* __restrict__ counts, int* __restrict__ bsums, int N) {
  int b = blockIdx.x, tid = threadIdx.x;
  int base = b * 1024 + tid * 4;
  int s = 0;
  if (base + 3 < N) {
    int4 v = *(const int4*)(counts + base);
    s = v.x + v.y + v.z + v.w;
  } else {
    for (int q = 0; q < 4; q++) { int idx = base + q; if (idx < N) s += counts[idx]; }
  }
#pragma unroll
  for (int o = 32; o >= 1; o >>= 1) s += __shfl_xor(s, o);
  __shared__ int ws[4];
  if ((tid & 63) == 0) ws[tid >> 6] = s;
  __syncthreads();
  if (tid == 0) bsums[b] = ws[0] + ws[1] + ws[2] + ws[3];
}

__launch_bounds__(1024)
__global__ void scan2_kernel(const int* __restrict__ bsums, int* __restrict__ bpre,
                             int* __restrict__ offsets, int NB, int N, int E) {
  int tid = threadIdx.x, lane = tid & 63, w = tid >> 6;
  int v = (tid < NB) ? bsums[tid] : 0;
  int incl = v;
#pragma unroll
  for (int o = 1; o < 64; o <<= 1) { int t = __shfl_up(incl, o); if (lane >= o) incl += t; }
  __shared__ int ws[16];
  if (lane == 63) ws[w] = incl;
  __syncthreads();
  int wpre = 0;
  for (int q = 0; q < w; q++) wpre += ws[q];
  if (tid < NB) bpre[tid] = wpre + incl - v;
  if (tid == 0) offsets[N] = E;
}

__launch_bounds__(256)
__global__ void scan3_kernel(const int* __restrict__ counts, const int* __restrict__ bpre,
                             int* __restrict__ offsets, int N) {
  int b = blockIdx.x, tid = threadIdx.x, lane = tid & 63, w = tid >> 6;
  int base = b * 1024 + tid * 4;
  int c[4] = {0, 0, 0, 0};
  if (base + 3 < N) {
    int4 v = *(const int4*)(counts + base);
    c[0] = v.x; c[1] = v.y; c[2] = v.z; c[3] = v.w;
  } else {
    for (int q = 0; q < 4; q++) { int idx = base + q; if (idx < N) c[q] = counts[idx]; }
  }
  int s = c[0] + c[1] + c[2] + c[3];
  int incl = s;
#pragma unroll
  for (int o = 1; o < 64; o <<= 1) { int t = __shfl_up(incl, o); if (lane >= o) incl += t; }
  int excl = incl - s;
  __shared__ int ws[4];
  if (lane == 63) ws[w] = incl;
  __syncthreads();
  int wpre = 0;
  for (int q = 0; q < w; q++) wpre += ws[q];
  int off = bpre[b] + wpre + excl;
  for (int q = 0; q < 4; q++) {
    int idx = base + q;
    if (idx < N) offsets[idx] = off;
    off += c[q];
  }
}

__global__ void fill_kernel(const int* __restrict__ src, const int* __restrict__ dst,
                            const int* __restrict__ offsets, int* __restrict__ cursor,
                            int* __restrict__ src_sorted, int* __restrict__ dst_sorted, int E) {
  int e = blockIdx.x * 256 + threadIdx.x;
  if (e < E) {
    int d = dst[e];
    int pos = offsets[d] + atomicAdd(&cursor[d], 1);
    src_sorted[pos] = src[e];
    dst_sorted[pos] = d;
  }
}

// ---------------- MFMA per-edge scores -> ek = exp(leaky_relu(mlp)) ----------------
// Wave handles 64 edges. A = relu(u[src]+v[dst]) is 64x256 fp16 built 32-k at a
// time in per-wave LDS scratch (80B row stride -> all 8 16B bank-columns hit);
// W2cat (256x8 block-diag) lives in registers as 8 B-fragments. 32 MFMA/wave
// replaces 512 dot2 + 128 w2-LDS-reads per *edge* (round-4: VALUBusy 67%).
__launch_bounds__(256, 4)
__global__ void score_kernel(const _Float16* __restrict__ u_cat, const _Float16* __restrict__ v_cat,
                             const int* __restrict__ src_sorted, const int* __restrict__ dst_sorted,
                             const float* __restrict__ w2a, const float* __restrict__ w2b,
                             const float* __restrict__ b2a, const float* __restrict__ b2b,
                             float* __restrict__ ek, int E) {
  // per-wave scratch: 64 rows x 40 halves (32 data + 8 pad) = 5120B; 4 waves = 20KB
  __shared__ _Float16 sA[4 * 64 * 40];
  int tid = threadIdx.x, lane = tid & 63, w = tid >> 6;
  int col = lane & 15, kg = lane >> 4;
  int ebase = blockIdx.x * 256 + w * 64;
  int e = ebase + lane;
  bool valid = e < E;
  int s = valid ? src_sorted[e] : 0;
  int d = valid ? dst_sorted[e] : 0;

  // B-fragments: bfrag[t] holds W2cat[k = t*32 + kg*8 + j][col], col<8 real, else 0
  fh8 bfrag[8];
#pragma unroll
  for (int t = 0; t < 8; t++) {
#pragma unroll
    for (int j = 0; j < 8; j++) {
      int k = t * 32 + kg * 8 + j;
      float wv = 0.f;
      if (col < 4) { if (k < 128) wv = w2a[k * 4 + col]; }
      else if (col < 8) { if (k >= 128) wv = w2b[(k - 128) * 4 + (col - 4)]; }
      bfrag[t][j] = (_Float16)wv;
    }
  }

  f32x4v acc[4];
#pragma unroll
  for (int m = 0; m < 4; m++) acc[m] = (f32x4v){0.f, 0.f, 0.f, 0.f};

  _Float16* myA = sA + w * (64 * 40);
  const fh8* up = (const fh8*)(u_cat + (size_t)s * 256);
  const fh8* vp = (const fh8*)(v_cat + (size_t)d * 256);

#pragma unroll 2
  for (int t = 0; t < 8; t++) {
    // build this wave's 64x32 A-chunk: relu(u+v), all packed f16 ops
    fh8 h0 = relu8(up[t * 4 + 0] + vp[t * 4 + 0]);
    fh8 h1 = relu8(up[t * 4 + 1] + vp[t * 4 + 1]);
    fh8 h2 = relu8(up[t * 4 + 2] + vp[t * 4 + 2]);
    fh8 h3 = relu8(up[t * 4 + 3] + vp[t * 4 + 3]);
    _Float16* rp = myA + lane * 40;
    *(fh8*)(rp + 0)  = h0;
    *(fh8*)(rp + 8)  = h1;
    *(fh8*)(rp + 16) = h2;
    *(fh8*)(rp + 24) = h3;
    // wave-local write->read fence (no __syncthreads: regions are per-wave)
    __builtin_amdgcn_wave_barrier();
    asm volatile("s_waitcnt lgkmcnt(0)" ::: "memory");
#pragma unroll
    for (int m = 0; m < 4; m++) {
      fh8 af = *(const fh8*)(myA + (m * 16 + col) * 40 + kg * 8);
      acc[m] = __builtin_amdgcn_mfma_f32_16x16x32_f16(af, bfrag[t], acc[m], 0, 0, 0);
    }
    __builtin_amdgcn_wave_barrier();   // keep next chunk's writes after these reads
  }

  // C layout: col = lane&15 (head), row = kg*4 + q (edge within 16-tile)  [m89/m91]
  if (col < 8) {
    float b2v = (col < 4) ? b2a[col] : b2b[col - 4];
#pragma unroll
    for (int m = 0; m < 4; m++) {
#pragma unroll
      for (int q = 0; q < 4; q++) {
        int er = ebase + m * 16 + kg * 4 + q;
        if (er < E) {
          float x = acc[m][q] + b2v;
          x = x > 0.f ? x : 0.01f * x;
          ek[(size_t)er * 8 + col] = __expf(x);
        }
      }
    }
  }
}

// ---------------- softmax-normalize + aggregate: one wave per dst node, ONE pass ----------------
__launch_bounds__(256)
__global__ void agg_kernel(const float* __restrict__ ek, const int* __restrict__ src_sorted,
                           const int* __restrict__ offsets, const _Float16* __restrict__ h16,
                           float* __restrict__ out, int N) {
  int wid = blockIdx.x * 4 + (threadIdx.x >> 6);
  int lane = threadIdx.x & 63;
  if (wid >= N) return;
  int off0 = offsets[wid], off1 = offsets[wid + 1];
  int deg = off1 - off0;
  float* op = out + (size_t)wid * 512;
  if (deg == 0) {
#pragma unroll
    for (int k = 0; k < 4; k++) { op[k * 128 + lane] = 0.f; op[k * 128 + 64 + lane] = 0.f; }
    return;
  }
  float accO[8] = {0, 0, 0, 0, 0, 0, 0, 0};
  float ssum[8] = {0, 0, 0, 0, 0, 0, 0, 0};
  int jj = 0;
  for (; jj + 2 <= deg; jj += 2) {
    size_t e0 = (size_t)(off0 + jj);
    const float4* p0 = (const float4*)(ek + e0 * 8);
    float4 a0 = p0[0], a1 = p0[1], b0 = p0[2], b1 = p0[3];
    int sa = src_sorted[e0], sb = src_sorted[e0 + 1];
    float hva = (float)h16[(size_t)sa * DH + lane];
    float hvb = (float)h16[(size_t)sb * DH + lane];
    accO[0] = fmaf(a0.x, hva, accO[0]); accO[1] = fmaf(a0.y, hva, accO[1]);
    accO[2] = fmaf(a0.z, hva, accO[2]); accO[3] = fmaf(a0.w, hva, accO[3]);
    accO[4] = fmaf(a1.x, hva, accO[4]); accO[5] = fmaf(a1.y, hva, accO[5]);
    accO[6] = fmaf(a1.z, hva, accO[6]); accO[7] = fmaf(a1.w, hva, accO[7]);
    accO[0] = fmaf(b0.x, hvb, accO[0]); accO[1] = fmaf(b0.y, hvb, accO[1]);
    accO[2] = fmaf(b0.z, hvb, accO[2]); accO[3] = fmaf(b0.w, hvb, accO[3]);
    accO[4] = fmaf(b1.x, hvb, accO[4]); accO[5] = fmaf(b1.y, hvb, accO[5]);
    accO[6] = fmaf(b1.z, hvb, accO[6]); accO[7] = fmaf(b1.w, hvb, accO[7]);
    ssum[0] += a0.x + b0.x; ssum[1] += a0.y + b0.y;
    ssum[2] += a0.z + b0.z; ssum[3] += a0.w + b0.w;
    ssum[4] += a1.x + b1.x; ssum[5] += a1.y + b1.y;
    ssum[6] += a1.z + b1.z; ssum[7] += a1.w + b1.w;
  }
  if (jj < deg) {
    size_t e0 = (size_t)(off0 + jj);
    const float4* p0 = (const float4*)(ek + e0 * 8);
    float4 a0 = p0[0], a1 = p0[1];
    int sa = src_sorted[e0];
    float hva = (float)h16[(size_t)sa * DH + lane];
    accO[0] = fmaf(a0.x, hva, accO[0]); accO[1] = fmaf(a0.y, hva, accO[1]);
    accO[2] = fmaf(a0.z, hva, accO[2]); accO[3] = fmaf(a0.w, hva, accO[3]);
    accO[4] = fmaf(a1.x, hva, accO[4]); accO[5] = fmaf(a1.y, hva, accO[5]);
    accO[6] = fmaf(a1.z, hva, accO[6]); accO[7] = fmaf(a1.w, hva, accO[7]);
    ssum[0] += a0.x; ssum[1] += a0.y; ssum[2] += a0.z; ssum[3] += a0.w;
    ssum[4] += a1.x; ssum[5] += a1.y; ssum[6] += a1.z; ssum[7] += a1.w;
  }
#pragma unroll
  for (int k = 0; k < 8; k++) {
    float rsv = 1.f / ssum[k];
    int col = k < 4 ? k * 128 + lane : (k - 4) * 128 + 64 + lane;
    op[col] = accO[k] * rsv;
  }
}

extern "C" void kernel_launch(void* const* d_in, const int* in_sizes, int n_in,
                              void* d_out, int out_size, void* d_ws, size_t ws_size,
                              hipStream_t stream) {
  const float* h      = (const float*)d_in[0];
  const float* pca    = (const float*)d_in[1];
  const float* pimg   = (const float*)d_in[2];
  const float* pca_w1 = (const float*)d_in[3];
  const float* pca_b1 = (const float*)d_in[4];
  const float* pca_w2 = (const float*)d_in[5];
  const float* pca_b2 = (const float*)d_in[6];
  const float* pi_w1  = (const float*)d_in[7];
  const float* pi_b1  = (const float*)d_in[8];
  const float* pi_w2  = (const float*)d_in[9];
  const float* pi_b2  = (const float*)d_in[10];
  const int*   src    = (const int*)d_in[11];
  const int*   dst    = (const int*)d_in[12];
  int N = in_sizes[0] / 64;
  int E = in_sizes[11];
  float* out = (float*)d_out;

  char* ws = (char*)d_ws;
  size_t o = 0;
  auto alloc = [&](size_t bytes) { void* p = ws + o; o += (bytes + 255) & ~(size_t)255; return p; };
  _Float16* u_cat = (_Float16*)alloc((size_t)N * 256 * 2);
  _Float16* v_cat = (_Float16*)alloc((size_t)N * 256 * 2);
  _Float16* h16   = (_Float16*)alloc((size_t)N * 64 * 2);
  int* counts  = (int*)alloc((size_t)N * 4);
  int* cursor  = (int*)alloc((size_t)N * 4);
  int* offsets = (int*)alloc((size_t)(N + 1) * 4);
  int* bsums   = (int*)alloc(1024 * 4);
  int* bpre    = (int*)alloc(1024 * 4);
  int* src_sorted = (int*)alloc((size_t)E * 4);
  int* dst_sorted = (int*)alloc((size_t)E * 4);
  float* ek       = (float*)alloc((size_t)E * 8 * 4);

  hipMemsetAsync(counts, 0, (size_t)N * 4, stream);
  hipMemsetAsync(cursor, 0, (size_t)N * 4, stream);

  uv_kernel<64, 32><<<(N + 31) / 32, 256, 0, stream>>>(pca, pca_w1, pca_b1, u_cat, v_cat, 0, N);
  uv_kernel<32, 32><<<(N + 31) / 32, 256, 0, stream>>>(pimg, pi_w1, pi_b1, u_cat, v_cat, 128, N);
  h16_kernel<<<((N * 64) / 4 + 255) / 256, 256, 0, stream>>>(h, h16, N * 64);
  count_kernel<<<(E + 255) / 256, 256, 0, stream>>>(dst, counts, E);
  int NB = (N + 1023) / 1024;
  scan1_kernel<<<NB, 256, 0, stream>>>(counts, bsums, N);
  scan2_kernel<<<1, 1024, 0, stream>>>(bsums, bpre, offsets, NB, N, E);
  scan3_kernel<<<NB, 256, 0, stream>>>(counts, bpre, offsets, N);
  fill_kernel<<<(E + 255) / 256, 256, 0, stream>>>(src, dst, offsets, cursor, src_sorted, dst_sorted, E);
  score_kernel<<<(E + 255) / 256, 256, 0, stream>>>(u_cat, v_cat, src_sorted, dst_sorted,
                                                    pca_w2, pi_w2, pca_b2, pi_b2, ek, E);
  agg_kernel<<<(N + 3) / 4, 256, 0, stream>>>(ek, src_sorted, offsets, h16, out, N);
}

// Round 6
// 356.169 us; speedup vs baseline: 1.3500x; 1.3500x over previous
//
#include <hip/hip_runtime.h>
#include <hip/hip_fp16.h>

constexpr int HID = 128;
constexpr int DH  = 64;

typedef _Float16 f16x2 __attribute__((ext_vector_type(2)));
typedef _Float16 fh8   __attribute__((ext_vector_type(8)));   // 4 VGPRs, MFMA A/B frag
typedef float    f32x4v __attribute__((ext_vector_type(4)));  // MFMA C/D frag

__device__ __forceinline__ fh8 relu8(fh8 x) {
  fh8 z = {0, 0, 0, 0, 0, 0, 0, 0};
#if __has_builtin(__builtin_elementwise_max)
  return __builtin_elementwise_max(x, z);
#else
  fh8 r;
#pragma unroll
  for (int i = 0; i < 8; i++) r[i] = x[i] > z[i] ? x[i] : z[i];
  return r;
#endif
}

// ---------------- uv precompute: u = feat @ W1_top, v = feat @ W1_bot + b1 ----------------
// concatenated tables: u_cat[n*256 + roff + j], roff = 0 (pca) / 128 (pimg)
template<int F, int NB>
__launch_bounds__(256)
__global__ void uv_kernel(const float* __restrict__ feat, const float* __restrict__ w1,
                          const float* __restrict__ b1,
                          _Float16* __restrict__ u_cat, _Float16* __restrict__ v_cat,
                          int roff, int N) {
  __shared__ float sfeat[NB][F + 1];
  int nb = blockIdx.x * NB;
  for (int i = threadIdx.x; i < NB * F; i += 256) {
    int n = i / F, k = i - n * F;
    int gn = nb + n;
    sfeat[n][k] = (gn < N) ? feat[(size_t)gn * F + k] : 0.f;
  }
  __syncthreads();
  int j = threadIdx.x & 127;
  int g = threadIdx.x >> 7;           // 0..1
  constexpr int NPT = NB / 2;
  float ua[NPT], va[NPT];
#pragma unroll
  for (int i = 0; i < NPT; i++) { ua[i] = 0.f; va[i] = 0.f; }
  for (int k = 0; k < F; k++) {
    float wu = w1[k * HID + j];
    float wv = w1[(F + k) * HID + j];
#pragma unroll
    for (int i = 0; i < NPT; i++) {
      float f = sfeat[g * NPT + i][k];
      ua[i] = fmaf(f, wu, ua[i]);
      va[i] = fmaf(f, wv, va[i]);
    }
  }
  float b1v = b1[j];
#pragma unroll
  for (int i = 0; i < NPT; i++) {
    int gn = nb + g * NPT + i;
    if (gn < N) {
      u_cat[(size_t)gn * 256 + roff + j] = (_Float16)ua[i];
      v_cat[(size_t)gn * 256 + roff + j] = (_Float16)(va[i] + b1v);
    }
  }
}

// ---------------- h -> fp16 copy ----------------
__global__ void h16_kernel(const float* __restrict__ h, _Float16* __restrict__ h16, int total) {
  int i = (blockIdx.x * 256 + threadIdx.x) * 4;
  if (i + 3 < total) {
    float4 v = *(const float4*)(h + i);
    h16[i] = (_Float16)v.x; h16[i + 1] = (_Float16)v.y;
    h16[i + 2] = (_Float16)v.z; h16[i + 3] = (_Float16)v.w;
  } else {
    for (int q = 0; q < 4; q++) if (i + q < total) h16[i + q] = (_Float16)h[i + q];
  }
}

// ---------------- CSR build ----------------
__global__ void count_kernel(const int* __restrict__ dst, int* __restrict__ counts, int E) {
  int e = blockIdx.x * 256 + threadIdx.x;
  if (e < E) atomicAdd(&counts[dst[e]], 1);
}

__launch_bounds__(256)
__global__ void scan1_kernel(const int* __restrict__ counts, int* __restrict__ bsums, int N) {
  int b = blockIdx.x, tid = threadIdx.x;
  int base = b * 1024 + tid * 4;
  int s = 0;
  if (base + 3 < N) {
    int4 v = *(const int4*)(counts + base);
    s = v.x + v.y + v.z + v.w;
  } else {
    for (int q = 0; q < 4; q++) { int idx = base + q; if (idx < N) s += counts[idx]; }
  }
#pragma unroll
  for (int o = 32; o >= 1; o >>= 1) s += __shfl_xor(s, o);
  __shared__ int ws[4];
  if ((tid & 63) == 0) ws[tid >> 6] = s;
  __syncthreads();
  if (tid == 0) bsums[b] = ws[0] + ws[1] + ws[2] + ws[3];
}

__launch_bounds__(1024)
__global__ void scan2_kernel(const int* __restrict__ bsums, int* __restrict__ bpre,
                             int* __restrict__ offsets, int NB, int N, int E) {
  int tid = threadIdx.x, lane = tid & 63, w = tid >> 6;
  int v = (tid < NB) ? bsums[tid] : 0;
  int incl = v;
#pragma unroll
  for (int o = 1; o < 64; o <<= 1) { int t = __shfl_up(incl, o); if (lane >= o) incl += t; }
  __shared__ int ws[16];
  if (lane == 63) ws[w] = incl;
  __syncthreads();
  int wpre = 0;
  for (int q = 0; q < w; q++) wpre += ws[q];
  if (tid < NB) bpre[tid] = wpre + incl - v;
  if (tid == 0) offsets[N] = E;
}

__launch_bounds__(256)
__global__ void scan3_kernel(const int* __restrict__ counts, const int* __restrict__ bpre,
                             int* __restrict__ offsets, int N) {
  int b = blockIdx.x, tid = threadIdx.x, lane = tid & 63, w = tid >> 6;
  int base = b * 1024 + tid * 4;
  int c[4] = {0, 0, 0, 0};
  if (base + 3 < N) {
    int4 v = *(const int4*)(counts + base);
    c[0] = v.x; c[1] = v.y; c[2] = v.z; c[3] = v.w;
  } else {
    for (int q = 0; q < 4; q++) { int idx = base + q; if (idx < N) c[q] = counts[idx]; }
  }
  int s = c[0] + c[1] + c[2] + c[3];
  int incl = s;
#pragma unroll
  for (int o = 1; o < 64; o <<= 1) { int t = __shfl_up(incl, o); if (lane >= o) incl += t; }
  int excl = incl - s;
  __shared__ int ws[4];
  if (lane == 63) ws[w] = incl;
  __syncthreads();
  int wpre = 0;
  for (int q = 0; q < w; q++) wpre += ws[q];
  int off = bpre[b] + wpre + excl;
  for (int q = 0; q < 4; q++) {
    int idx = base + q;
    if (idx < N) offsets[idx] = off;
    off += c[q];
  }
}

__global__ void fill_kernel(const int* __restrict__ src, const int* __restrict__ dst,
                            const int* __restrict__ offsets, int* __restrict__ cursor,
                            int* __restrict__ src_sorted, int* __restrict__ dst_sorted, int E) {
  int e = blockIdx.x * 256 + threadIdx.x;
  if (e < E) {
    int d = dst[e];
    int pos = offsets[d] + atomicAdd(&cursor[d], 1);
    src_sorted[pos] = src[e];
    dst_sorted[pos] = d;
  }
}

// ---------------- MFMA per-edge scores -> ek = exp(leaky_relu(mlp)), fp16 ----------------
// Round-5 lesson: LDS staging for A cost 1.6M bank conflicts + lgkmcnt serialization.
// Now the gather itself produces the A fragment: lane (col,kg) loads 16B of edge
// (m*16+col)'s u/v rows at k-offset kg*8. Zero LDS, zero barriers; B (w2) stays in
// 32 VGPRs; 64x16B gathers + 32 MFMA per wave replace round-4's ~930 VALU ops/edge.
__launch_bounds__(256, 4)
__global__ void score_kernel(const _Float16* __restrict__ u_cat, const _Float16* __restrict__ v_cat,
                             const int* __restrict__ src_sorted, const int* __restrict__ dst_sorted,
                             const float* __restrict__ w2a, const float* __restrict__ w2b,
                             const float* __restrict__ b2a, const float* __restrict__ b2b,
                             _Float16* __restrict__ ek, int E) {
  int tid = threadIdx.x, lane = tid & 63, w = tid >> 6;
  int col = lane & 15, kg = lane >> 4;
  int ebase = blockIdx.x * 256 + w * 64;

  // B-fragments: bfrag[t][j] = W2cat[k = t*32 + kg*8 + j][col] (block-diag, col<8 real)
  fh8 bfrag[8];
#pragma unroll
  for (int t = 0; t < 8; t++) {
#pragma unroll
    for (int j = 0; j < 8; j++) {
      int k = t * 32 + kg * 8 + j;
      float wv = 0.f;
      if (col < 4) { if (k < 128) wv = w2a[k * 4 + col]; }
      else if (col < 8) { if (k >= 128) wv = w2b[(k - 128) * 4 + (col - 4)]; }
      bfrag[t][j] = (_Float16)wv;
    }
  }

  // fragment-layout gather pointers: lane serves edge (m*16+col) at k-offset kg*8
  const _Float16* up[4];
  const _Float16* vp[4];
#pragma unroll
  for (int m = 0; m < 4; m++) {
    int em = ebase + m * 16 + col;
    int ec = em < E ? em : 0;          // clamp; epilogue guards stores
    int s = src_sorted[ec], d = dst_sorted[ec];
    up[m] = u_cat + (size_t)s * 256 + kg * 8;
    vp[m] = v_cat + (size_t)d * 256 + kg * 8;
  }

  f32x4v acc[4];
#pragma unroll
  for (int m = 0; m < 4; m++) acc[m] = (f32x4v){0.f, 0.f, 0.f, 0.f};

#pragma unroll
  for (int t = 0; t < 8; t++) {
#pragma unroll
    for (int m = 0; m < 4; m++) {
      fh8 uu = *(const fh8*)(up[m] + t * 32);
      fh8 vv = *(const fh8*)(vp[m] + t * 32);
      fh8 af = relu8(uu + vv);
      acc[m] = __builtin_amdgcn_mfma_f32_16x16x32_f16(af, bfrag[t], acc[m], 0, 0, 0);
    }
  }

  // C layout: col = lane&15 (head), row = kg*4 + q (edge within 16-tile)  [m89/m91]
  if (col < 8) {
    float b2v = (col < 4) ? b2a[col] : b2b[col - 4];
#pragma unroll
    for (int m = 0; m < 4; m++) {
#pragma unroll
      for (int q = 0; q < 4; q++) {
        int er = ebase + m * 16 + kg * 4 + q;
        if (er < E) {
          float x = acc[m][q] + b2v;
          x = x > 0.f ? x : 0.01f * x;
          ek[(size_t)er * 8 + col] = (_Float16)__expf(x);
        }
      }
    }
  }
}

// ---------------- softmax-normalize + aggregate: one wave per dst node, ONE pass ----------------
__launch_bounds__(256)
__global__ void agg_kernel(const _Float16* __restrict__ ek, const int* __restrict__ src_sorted,
                           const int* __restrict__ offsets, const _Float16* __restrict__ h16,
                           float* __restrict__ out, int N) {
  int wid = blockIdx.x * 4 + (threadIdx.x >> 6);
  int lane = threadIdx.x & 63;
  if (wid >= N) return;
  int off0 = offsets[wid], off1 = offsets[wid + 1];
  int deg = off1 - off0;
  float* op = out + (size_t)wid * 512;
  if (deg == 0) {
#pragma unroll
    for (int k = 0; k < 4; k++) { op[k * 128 + lane] = 0.f; op[k * 128 + 64 + lane] = 0.f; }
    return;
  }
  float accO[8] = {0, 0, 0, 0, 0, 0, 0, 0};
  float ssum[8] = {0, 0, 0, 0, 0, 0, 0, 0};
  int jj = 0;
  for (; jj + 2 <= deg; jj += 2) {
    size_t e0 = (size_t)(off0 + jj);
    fh8 ea = *(const fh8*)(ek + e0 * 8);
    fh8 eb = *(const fh8*)(ek + (e0 + 1) * 8);
    int sa = src_sorted[e0], sb = src_sorted[e0 + 1];
    float hva = (float)h16[(size_t)sa * DH + lane];
    float hvb = (float)h16[(size_t)sb * DH + lane];
#pragma unroll
    for (int k = 0; k < 8; k++) {
      float eav = (float)ea[k], ebv = (float)eb[k];
      accO[k] = fmaf(eav, hva, accO[k]);
      accO[k] = fmaf(ebv, hvb, accO[k]);
      ssum[k] += eav + ebv;
    }
  }
  if (jj < deg) {
    size_t e0 = (size_t)(off0 + jj);
    fh8 ea = *(const fh8*)(ek + e0 * 8);
    int sa = src_sorted[e0];
    float hva = (float)h16[(size_t)sa * DH + lane];
#pragma unroll
    for (int k = 0; k < 8; k++) {
      float eav = (float)ea[k];
      accO[k] = fmaf(eav, hva, accO[k]);
      ssum[k] += eav;
    }
  }
#pragma unroll
  for (int k = 0; k < 8; k++) {
    float rsv = 1.f / ssum[k];
    int col = k < 4 ? k * 128 + lane : (k - 4) * 128 + 64 + lane;
    op[col] = accO[k] * rsv;
  }
}

extern "C" void kernel_launch(void* const* d_in, const int* in_sizes, int n_in,
                              void* d_out, int out_size, void* d_ws, size_t ws_size,
                              hipStream_t stream) {
  const float* h      = (const float*)d_in[0];
  const float* pca    = (const float*)d_in[1];
  const float* pimg   = (const float*)d_in[2];
  const float* pca_w1 = (const float*)d_in[3];
  const float* pca_b1 = (const float*)d_in[4];
  const float* pca_w2 = (const float*)d_in[5];
  const float* pca_b2 = (const float*)d_in[6];
  const float* pi_w1  = (const float*)d_in[7];
  const float* pi_b1  = (const float*)d_in[8];
  const float* pi_w2  = (const float*)d_in[9];
  const float* pi_b2  = (const float*)d_in[10];
  const int*   src    = (const int*)d_in[11];
  const int*   dst    = (const int*)d_in[12];
  int N = in_sizes[0] / 64;
  int E = in_sizes[11];
  float* out = (float*)d_out;

  char* ws = (char*)d_ws;
  size_t o = 0;
  auto alloc = [&](size_t bytes) { void* p = ws + o; o += (bytes + 255) & ~(size_t)255; return p; };
  _Float16* u_cat = (_Float16*)alloc((size_t)N * 256 * 2);
  _Float16* v_cat = (_Float16*)alloc((size_t)N * 256 * 2);
  _Float16* h16   = (_Float16*)alloc((size_t)N * 64 * 2);
  int* counts  = (int*)alloc((size_t)N * 4);
  int* cursor  = (int*)alloc((size_t)N * 4);
  int* offsets = (int*)alloc((size_t)(N + 1) * 4);
  int* bsums   = (int*)alloc(1024 * 4);
  int* bpre    = (int*)alloc(1024 * 4);
  int* src_sorted = (int*)alloc((size_t)E * 4);
  int* dst_sorted = (int*)alloc((size_t)E * 4);
  _Float16* ekb   = (_Float16*)alloc((size_t)E * 8 * 2);

  hipMemsetAsync(counts, 0, (size_t)N * 4, stream);
  hipMemsetAsync(cursor, 0, (size_t)N * 4, stream);

  uv_kernel<64, 32><<<(N + 31) / 32, 256, 0, stream>>>(pca, pca_w1, pca_b1, u_cat, v_cat, 0, N);
  uv_kernel<32, 32><<<(N + 31) / 32, 256, 0, stream>>>(pimg, pi_w1, pi_b1, u_cat, v_cat, 128, N);
  h16_kernel<<<((N * 64) / 4 + 255) / 256, 256, 0, stream>>>(h, h16, N * 64);
  count_kernel<<<(E + 255) / 256, 256, 0, stream>>>(dst, counts, E);
  int NB = (N + 1023) / 1024;
  scan1_kernel<<<NB, 256, 0, stream>>>(counts, bsums, N);
  scan2_kernel<<<1, 1024, 0, stream>>>(bsums, bpre, offsets, NB, N, E);
  scan3_kernel<<<NB, 256, 0, stream>>>(counts, bpre, offsets, N);
  fill_kernel<<<(E + 255) / 256, 256, 0, stream>>>(src, dst, offsets, cursor, src_sorted, dst_sorted, E);
  score_kernel<<<(E + 255) / 256, 256, 0, stream>>>(u_cat, v_cat, src_sorted, dst_sorted,
                                                    pca_w2, pi_w2, pca_b2, pi_b2, ekb, E);
  agg_kernel<<<(N + 3) / 4, 256, 0, stream>>>(ekb, src_sorted, offsets, h16, out, N);
}

// Round 7
// 336.442 us; speedup vs baseline: 1.4292x; 1.0586x over previous
//
#include <hip/hip_runtime.h>
#include <hip/hip_fp16.h>

constexpr int HID = 128;
constexpr int DH  = 64;

typedef _Float16 f16x2 __attribute__((ext_vector_type(2)));
typedef _Float16 fh8   __attribute__((ext_vector_type(8)));   // 4 VGPRs, MFMA A/B frag
typedef float    f32x4v __attribute__((ext_vector_type(4)));  // MFMA C/D frag

__device__ __forceinline__ fh8 relu8(fh8 x) {
  fh8 z = {0, 0, 0, 0, 0, 0, 0, 0};
#if __has_builtin(__builtin_elementwise_max)
  return __builtin_elementwise_max(x, z);
#else
  fh8 r;
#pragma unroll
  for (int i = 0; i < 8; i++) r[i] = x[i] > z[i] ? x[i] : z[i];
  return r;
#endif
}

// ---------------- uv precompute: u = feat @ W1_top, v = feat @ W1_bot + b1 ----------------
template<int F, int NB>
__launch_bounds__(256)
__global__ void uv_kernel(const float* __restrict__ feat, const float* __restrict__ w1,
                          const float* __restrict__ b1,
                          _Float16* __restrict__ u_cat, _Float16* __restrict__ v_cat,
                          int roff, int N) {
  __shared__ float sfeat[NB][F + 1];
  int nb = blockIdx.x * NB;
  for (int i = threadIdx.x; i < NB * F; i += 256) {
    int n = i / F, k = i - n * F;
    int gn = nb + n;
    sfeat[n][k] = (gn < N) ? feat[(size_t)gn * F + k] : 0.f;
  }
  __syncthreads();
  int j = threadIdx.x & 127;
  int g = threadIdx.x >> 7;           // 0..1
  constexpr int NPT = NB / 2;
  float ua[NPT], va[NPT];
#pragma unroll
  for (int i = 0; i < NPT; i++) { ua[i] = 0.f; va[i] = 0.f; }
  for (int k = 0; k < F; k++) {
    float wu = w1[k * HID + j];
    float wv = w1[(F + k) * HID + j];
#pragma unroll
    for (int i = 0; i < NPT; i++) {
      float f = sfeat[g * NPT + i][k];
      ua[i] = fmaf(f, wu, ua[i]);
      va[i] = fmaf(f, wv, va[i]);
    }
  }
  float b1v = b1[j];
#pragma unroll
  for (int i = 0; i < NPT; i++) {
    int gn = nb + g * NPT + i;
    if (gn < N) {
      u_cat[(size_t)gn * 256 + roff + j] = (_Float16)ua[i];
      v_cat[(size_t)gn * 256 + roff + j] = (_Float16)(va[i] + b1v);
    }
  }
}

// ---------------- h -> fp16 copy ----------------
__global__ void h16_kernel(const float* __restrict__ h, _Float16* __restrict__ h16, int total) {
  int i = (blockIdx.x * 256 + threadIdx.x) * 4;
  if (i + 3 < total) {
    float4 v = *(const float4*)(h + i);
    h16[i] = (_Float16)v.x; h16[i + 1] = (_Float16)v.y;
    h16[i + 2] = (_Float16)v.z; h16[i + 3] = (_Float16)v.w;
  } else {
    for (int q = 0; q < 4; q++) if (i + q < total) h16[i + q] = (_Float16)h[i + q];
  }
}

// ---------------- CSR build ----------------
__global__ void count_kernel(const int* __restrict__ dst, int* __restrict__ counts, int E) {
  int e = blockIdx.x * 256 + threadIdx.x;
  if (e < E) atomicAdd(&counts[dst[e]], 1);
}

__launch_bounds__(256)
__global__ void scan1_kernel(const int* __restrict__ counts, int* __restrict__ bsums, int N) {
  int b = blockIdx.x, tid = threadIdx.x;
  int base = b * 1024 + tid * 4;
  int s = 0;
  if (base + 3 < N) {
    int4 v = *(const int4*)(counts + base);
    s = v.x + v.y + v.z + v.w;
  } else {
    for (int q = 0; q < 4; q++) { int idx = base + q; if (idx < N) s += counts[idx]; }
  }
#pragma unroll
  for (int o = 32; o >= 1; o >>= 1) s += __shfl_xor(s, o);
  __shared__ int ws[4];
  if ((tid & 63) == 0) ws[tid >> 6] = s;
  __syncthreads();
  if (tid == 0) bsums[b] = ws[0] + ws[1] + ws[2] + ws[3];
}

__launch_bounds__(1024)
__global__ void scan2_kernel(const int* __restrict__ bsums, int* __restrict__ bpre,
                             int* __restrict__ offsets, int NB, int N, int E) {
  int tid = threadIdx.x, lane = tid & 63, w = tid >> 6;
  int v = (tid < NB) ? bsums[tid] : 0;
  int incl = v;
#pragma unroll
  for (int o = 1; o < 64; o <<= 1) { int t = __shfl_up(incl, o); if (lane >= o) incl += t; }
  __shared__ int ws[16];
  if (lane == 63) ws[w] = incl;
  __syncthreads();
  int wpre = 0;
  for (int q = 0; q < w; q++) wpre += ws[q];
  if (tid < NB) bpre[tid] = wpre + incl - v;
  if (tid == 0) offsets[N] = E;
}

__launch_bounds__(256)
__global__ void scan3_kernel(const int* __restrict__ counts, const int* __restrict__ bpre,
                             int* __restrict__ offsets, int N) {
  int b = blockIdx.x, tid = threadIdx.x, lane = tid & 63, w = tid >> 6;
  int base = b * 1024 + tid * 4;
  int c[4] = {0, 0, 0, 0};
  if (base + 3 < N) {
    int4 v = *(const int4*)(counts + base);
    c[0] = v.x; c[1] = v.y; c[2] = v.z; c[3] = v.w;
  } else {
    for (int q = 0; q < 4; q++) { int idx = base + q; if (idx < N) c[q] = counts[idx]; }
  }
  int s = c[0] + c[1] + c[2] + c[3];
  int incl = s;
#pragma unroll
  for (int o = 1; o < 64; o <<= 1) { int t = __shfl_up(incl, o); if (lane >= o) incl += t; }
  int excl = incl - s;
  __shared__ int ws[4];
  if (lane == 63) ws[w] = incl;
  __syncthreads();
  int wpre = 0;
  for (int q = 0; q < w; q++) wpre += ws[q];
  int off = bpre[b] + wpre + excl;
  for (int q = 0; q < 4; q++) {
    int idx = base + q;
    if (idx < N) offsets[idx] = off;
    off += c[q];
  }
}

// cursor pre-seeded with offsets (d2d memcpy) -> single atomic, no offsets read
__global__ void fill_kernel(const int* __restrict__ src, const int* __restrict__ dst,
                            int* __restrict__ cursor, int2* __restrict__ edges, int E) {
  int e = blockIdx.x * 256 + threadIdx.x;
  if (e < E) {
    int d = dst[e];
    int pos = atomicAdd(&cursor[d], 1);
    edges[pos] = make_int2(src[e], d);
  }
}

// ---------------- MFMA per-edge scores -> ek = exp(leaky_relu(mlp)), fp16 ----------------
// Round-6 lesson: load->mfma distance 0 + 8 in-flight loads/wave = latency-bound
// (VALUBusy 13%, VGPR 40). Now: w2 B-frags from an LDS table (frees 28 VGPR),
// explicit 2-deep t-prefetch (16 outstanding gathers/wave, use distance = 2 iters),
// launch_bounds(256,3) for the staging registers.
__launch_bounds__(256, 3)
__global__ void score_kernel(const _Float16* __restrict__ u_cat, const _Float16* __restrict__ v_cat,
                             const int2* __restrict__ edges,
                             const float* __restrict__ w2a, const float* __restrict__ w2b,
                             const float* __restrict__ b2a, const float* __restrict__ b2b,
                             _Float16* __restrict__ ek, int E) {
  __shared__ _Float16 sB[8 * 64 * 8];   // [t][lane][j] B-fragments of W2cat (block-diag)
  int tid = threadIdx.x, lane = tid & 63, w = tid >> 6;
  int col = lane & 15, kg = lane >> 4;
  for (int idx = tid; idx < 4096; idx += 256) {
    int t = idx >> 9, l = (idx >> 3) & 63, j = idx & 7;
    int bc = l & 15;
    int k = t * 32 + ((l >> 4) << 3) + j;
    float val = 0.f;
    if (bc < 4) { if (k < 128) val = w2a[k * 4 + bc]; }
    else if (bc < 8) { if (k >= 128) val = w2b[(k - 128) * 4 + (bc - 4)]; }
    sB[idx] = (_Float16)val;
  }
  __syncthreads();

  int ebase = blockIdx.x * 256 + w * 64;

  // fragment-layout gather pointers: lane (col,kg) serves edge (m*16+col), k-offset kg*8
  const _Float16* up[4];
  const _Float16* vp[4];
#pragma unroll
  for (int m = 0; m < 4; m++) {
    int em = ebase + m * 16 + col;
    int ec = em < E ? em : 0;          // clamp; epilogue guards stores
    int2 sd = edges[ec];
    up[m] = u_cat + (size_t)sd.x * 256 + kg * 8;
    vp[m] = v_cat + (size_t)sd.y * 256 + kg * 8;
  }

  f32x4v acc[4];
#pragma unroll
  for (int m = 0; m < 4; m++) acc[m] = (f32x4v){0.f, 0.f, 0.f, 0.f};

  // 2-deep software pipeline over t (k-chunks of 32)
  fh8 u0[4], v0[4], u1[4], v1[4];
#pragma unroll
  for (int m = 0; m < 4; m++) {
    u0[m] = *(const fh8*)(up[m]);
    v0[m] = *(const fh8*)(vp[m]);
    u1[m] = *(const fh8*)(up[m] + 32);
    v1[m] = *(const fh8*)(vp[m] + 32);
  }
#pragma unroll
  for (int t = 0; t < 8; t++) {
    fh8 cu[4], cv[4];
#pragma unroll
    for (int m = 0; m < 4; m++) { cu[m] = u0[m]; cv[m] = v0[m]; u0[m] = u1[m]; v0[m] = v1[m]; }
    if (t < 6) {
#pragma unroll
      for (int m = 0; m < 4; m++) {
        u1[m] = *(const fh8*)(up[m] + (t + 2) * 32);
        v1[m] = *(const fh8*)(vp[m] + (t + 2) * 32);
      }
    }
    fh8 bf = *(const fh8*)(sB + ((t * 64 + lane) << 3));
#pragma unroll
    for (int m = 0; m < 4; m++)
      acc[m] = __builtin_amdgcn_mfma_f32_16x16x32_f16(relu8(cu[m] + cv[m]), bf, acc[m], 0, 0, 0);
  }

  // C layout: col = lane&15 (head), row = kg*4 + q (edge within 16-tile)  [m89/m91]
  if (col < 8) {
    float b2v = (col < 4) ? b2a[col] : b2b[col - 4];
#pragma unroll
    for (int m = 0; m < 4; m++) {
#pragma unroll
      for (int q = 0; q < 4; q++) {
        int er = ebase + m * 16 + kg * 4 + q;
        if (er < E) {
          float x = acc[m][q] + b2v;
          x = x > 0.f ? x : 0.01f * x;
          ek[(size_t)er * 8 + col] = (_Float16)__expf(x);
        }
      }
    }
  }
}

// ---------------- softmax-normalize + aggregate: one wave per dst node, ONE pass ----------------
// 4-edge unroll: 4 independent src->h load chains + 4 ek loads in flight per iter
__launch_bounds__(256)
__global__ void agg_kernel(const _Float16* __restrict__ ek, const int2* __restrict__ edges,
                           const int* __restrict__ offsets, const _Float16* __restrict__ h16,
                           float* __restrict__ out, int N) {
  int wid = blockIdx.x * 4 + (threadIdx.x >> 6);
  int lane = threadIdx.x & 63;
  if (wid >= N) return;
  int off0 = offsets[wid], off1 = offsets[wid + 1];
  int deg = off1 - off0;
  float* op = out + (size_t)wid * 512;
  if (deg == 0) {
#pragma unroll
    for (int k = 0; k < 4; k++) { op[k * 128 + lane] = 0.f; op[k * 128 + 64 + lane] = 0.f; }
    return;
  }
  float accO[8] = {0, 0, 0, 0, 0, 0, 0, 0};
  float ssum[8] = {0, 0, 0, 0, 0, 0, 0, 0};
  int last = off1 - 1;
  for (int jj = 0; jj < deg; jj += 4) {
    int i0 = off0 + jj;
    int i1 = min(i0 + 1, last), i2 = min(i0 + 2, last), i3 = min(i0 + 3, last);
    bool m1 = jj + 1 < deg, m2 = jj + 2 < deg, m3 = jj + 3 < deg;
    int s0 = edges[i0].x, s1 = edges[i1].x, s2 = edges[i2].x, s3 = edges[i3].x;
    fh8 e0 = *(const fh8*)(ek + (size_t)i0 * 8);
    fh8 e1 = *(const fh8*)(ek + (size_t)i1 * 8);
    fh8 e2 = *(const fh8*)(ek + (size_t)i2 * 8);
    fh8 e3 = *(const fh8*)(ek + (size_t)i3 * 8);
    float hv0 = (float)h16[(size_t)s0 * DH + lane];
    float hv1 = (float)h16[(size_t)s1 * DH + lane];
    float hv2 = (float)h16[(size_t)s2 * DH + lane];
    float hv3 = (float)h16[(size_t)s3 * DH + lane];
#pragma unroll
    for (int k = 0; k < 8; k++) {
      float e0v = (float)e0[k];
      float e1v = m1 ? (float)e1[k] : 0.f;
      float e2v = m2 ? (float)e2[k] : 0.f;
      float e3v = m3 ? (float)e3[k] : 0.f;
      accO[k] = fmaf(e0v, hv0, accO[k]);
      accO[k] = fmaf(e1v, hv1, accO[k]);
      accO[k] = fmaf(e2v, hv2, accO[k]);
      accO[k] = fmaf(e3v, hv3, accO[k]);
      ssum[k] += (e0v + e1v) + (e2v + e3v);
    }
  }
#pragma unroll
  for (int k = 0; k < 8; k++) {
    float rsv = 1.f / ssum[k];
    int colo = k < 4 ? k * 128 + lane : (k - 4) * 128 + 64 + lane;
    op[colo] = accO[k] * rsv;
  }
}

extern "C" void kernel_launch(void* const* d_in, const int* in_sizes, int n_in,
                              void* d_out, int out_size, void* d_ws, size_t ws_size,
                              hipStream_t stream) {
  const float* h      = (const float*)d_in[0];
  const float* pca    = (const float*)d_in[1];
  const float* pimg   = (const float*)d_in[2];
  const float* pca_w1 = (const float*)d_in[3];
  const float* pca_b1 = (const float*)d_in[4];
  const float* pca_w2 = (const float*)d_in[5];
  const float* pca_b2 = (const float*)d_in[6];
  const float* pi_w1  = (const float*)d_in[7];
  const float* pi_b1  = (const float*)d_in[8];
  const float* pi_w2  = (const float*)d_in[9];
  const float* pi_b2  = (const float*)d_in[10];
  const int*   src    = (const int*)d_in[11];
  const int*   dst    = (const int*)d_in[12];
  int N = in_sizes[0] / 64;
  int E = in_sizes[11];
  float* out = (float*)d_out;

  char* ws = (char*)d_ws;
  size_t o = 0;
  auto alloc = [&](size_t bytes) { void* p = ws + o; o += (bytes + 255) & ~(size_t)255; return p; };
  _Float16* u_cat = (_Float16*)alloc((size_t)N * 256 * 2);
  _Float16* v_cat = (_Float16*)alloc((size_t)N * 256 * 2);
  _Float16* h16   = (_Float16*)alloc((size_t)N * 64 * 2);
  int* counts  = (int*)alloc((size_t)N * 4);
  int* cursor  = (int*)alloc((size_t)N * 4);
  int* offsets = (int*)alloc((size_t)(N + 1) * 4);
  int* bsums   = (int*)alloc(1024 * 4);
  int* bpre    = (int*)alloc(1024 * 4);
  int2* edges  = (int2*)alloc((size_t)E * 8);
  _Float16* ekb = (_Float16*)alloc((size_t)E * 8 * 2);

  hipMemsetAsync(counts, 0, (size_t)N * 4, stream);

  uv_kernel<64, 32><<<(N + 31) / 32, 256, 0, stream>>>(pca, pca_w1, pca_b1, u_cat, v_cat, 0, N);
  uv_kernel<32, 32><<<(N + 31) / 32, 256, 0, stream>>>(pimg, pi_w1, pi_b1, u_cat, v_cat, 128, N);
  h16_kernel<<<((N * 64) / 4 + 255) / 256, 256, 0, stream>>>(h, h16, N * 64);
  count_kernel<<<(E + 255) / 256, 256, 0, stream>>>(dst, counts, E);
  int NB = (N + 1023) / 1024;
  scan1_kernel<<<NB, 256, 0, stream>>>(counts, bsums, N);
  scan2_kernel<<<1, 1024, 0, stream>>>(bsums, bpre, offsets, NB, N, E);
  scan3_kernel<<<NB, 256, 0, stream>>>(counts, bpre, offsets, N);
  hipMemcpyAsync(cursor, offsets, (size_t)N * 4, hipMemcpyDeviceToDevice, stream);
  fill_kernel<<<(E + 255) / 256, 256, 0, stream>>>(src, dst, cursor, edges, E);
  score_kernel<<<(E + 255) / 256, 256, 0, stream>>>(u_cat, v_cat, edges,
                                                    pca_w2, pi_w2, pca_b2, pi_b2, ekb, E);
  agg_kernel<<<(N + 3) / 4, 256, 0, stream>>>(ekb, edges, offsets, h16, out, N);
}

// Round 8
// 323.087 us; speedup vs baseline: 1.4882x; 1.0413x over previous
//
#include <hip/hip_runtime.h>
#include <hip/hip_fp16.h>

constexpr int HID = 128;
constexpr int DH  = 64;

typedef _Float16 f16x2 __attribute__((ext_vector_type(2)));
typedef _Float16 fh8   __attribute__((ext_vector_type(8)));   // 4 VGPRs, MFMA A/B frag
typedef float    f32x4v __attribute__((ext_vector_type(4)));  // MFMA C/D frag

__device__ __forceinline__ fh8 relu8(fh8 x) {
  fh8 z = {0, 0, 0, 0, 0, 0, 0, 0};
#if __has_builtin(__builtin_elementwise_max)
  return __builtin_elementwise_max(x, z);
#else
  fh8 r;
#pragma unroll
  for (int i = 0; i < 8; i++) r[i] = x[i] > z[i] ? x[i] : z[i];
  return r;
#endif
}

// ---------------- uv precompute: u = feat @ W1_top, v = feat @ W1_bot + b1 ----------------
template<int F, int NB>
__launch_bounds__(256)
__global__ void uv_kernel(const float* __restrict__ feat, const float* __restrict__ w1,
                          const float* __restrict__ b1,
                          _Float16* __restrict__ u_cat, _Float16* __restrict__ v_cat,
                          int roff, int N) {
  __shared__ float sfeat[NB][F + 1];
  int nb = blockIdx.x * NB;
  for (int i = threadIdx.x; i < NB * F; i += 256) {
    int n = i / F, k = i - n * F;
    int gn = nb + n;
    sfeat[n][k] = (gn < N) ? feat[(size_t)gn * F + k] : 0.f;
  }
  __syncthreads();
  int j = threadIdx.x & 127;
  int g = threadIdx.x >> 7;           // 0..1
  constexpr int NPT = NB / 2;
  float ua[NPT], va[NPT];
#pragma unroll
  for (int i = 0; i < NPT; i++) { ua[i] = 0.f; va[i] = 0.f; }
  for (int k = 0; k < F; k++) {
    float wu = w1[k * HID + j];
    float wv = w1[(F + k) * HID + j];
#pragma unroll
    for (int i = 0; i < NPT; i++) {
      float f = sfeat[g * NPT + i][k];
      ua[i] = fmaf(f, wu, ua[i]);
      va[i] = fmaf(f, wv, va[i]);
    }
  }
  float b1v = b1[j];
#pragma unroll
  for (int i = 0; i < NPT; i++) {
    int gn = nb + g * NPT + i;
    if (gn < N) {
      u_cat[(size_t)gn * 256 + roff + j] = (_Float16)ua[i];
      v_cat[(size_t)gn * 256 + roff + j] = (_Float16)(va[i] + b1v);
    }
  }
}

// ---------------- h -> fp16 copy ----------------
__global__ void h16_kernel(const float* __restrict__ h, _Float16* __restrict__ h16, int total) {
  int i = (blockIdx.x * 256 + threadIdx.x) * 4;
  if (i + 3 < total) {
    float4 v = *(const float4*)(h + i);
    h16[i] = (_Float16)v.x; h16[i + 1] = (_Float16)v.y;
    h16[i + 2] = (_Float16)v.z; h16[i + 3] = (_Float16)v.w;
  } else {
    for (int q = 0; q < 4; q++) if (i + q < total) h16[i + q] = (_Float16)h[i + q];
  }
}

// ---------------- CSR build ----------------
__global__ void count_kernel(const int* __restrict__ dst, int* __restrict__ counts, int E) {
  int e = blockIdx.x * 256 + threadIdx.x;
  if (e < E) atomicAdd(&counts[dst[e]], 1);
}

__launch_bounds__(256)
__global__ void scan1_kernel(const int* __restrict__ counts, int* __restrict__ bsums, int N) {
  int b = blockIdx.x, tid = threadIdx.x;
  int base = b * 1024 + tid * 4;
  int s = 0;
  if (base + 3 < N) {
    int4 v = *(const int4*)(counts + base);
    s = v.x + v.y + v.z + v.w;
  } else {
    for (int q = 0; q < 4; q++) { int idx = base + q; if (idx < N) s += counts[idx]; }
  }
#pragma unroll
  for (int o = 32; o >= 1; o >>= 1) s += __shfl_xor(s, o);
  __shared__ int ws[4];
  if ((tid & 63) == 0) ws[tid >> 6] = s;
  __syncthreads();
  if (tid == 0) bsums[b] = ws[0] + ws[1] + ws[2] + ws[3];
}

__launch_bounds__(1024)
__global__ void scan2_kernel(const int* __restrict__ bsums, int* __restrict__ bpre,
                             int* __restrict__ offsets, int NB, int N, int E) {
  int tid = threadIdx.x, lane = tid & 63, w = tid >> 6;
  int v = (tid < NB) ? bsums[tid] : 0;
  int incl = v;
#pragma unroll
  for (int o = 1; o < 64; o <<= 1) { int t = __shfl_up(incl, o); if (lane >= o) incl += t; }
  __shared__ int ws[16];
  if (lane == 63) ws[w] = incl;
  __syncthreads();
  int wpre = 0;
  for (int q = 0; q < w; q++) wpre += ws[q];
  if (tid < NB) bpre[tid] = wpre + incl - v;
  if (tid == 0) offsets[N] = E;
}

__launch_bounds__(256)
__global__ void scan3_kernel(const int* __restrict__ counts, const int* __restrict__ bpre,
                             int* __restrict__ offsets, int N) {
  int b = blockIdx.x, tid = threadIdx.x, lane = tid & 63, w = tid >> 6;
  int base = b * 1024 + tid * 4;
  int c[4] = {0, 0, 0, 0};
  if (base + 3 < N) {
    int4 v = *(const int4*)(counts + base);
    c[0] = v.x; c[1] = v.y; c[2] = v.z; c[3] = v.w;
  } else {
    for (int q = 0; q < 4; q++) { int idx = base + q; if (idx < N) c[q] = counts[idx]; }
  }
  int s = c[0] + c[1] + c[2] + c[3];
  int incl = s;
#pragma unroll
  for (int o = 1; o < 64; o <<= 1) { int t = __shfl_up(incl, o); if (lane >= o) incl += t; }
  int excl = incl - s;
  __shared__ int ws[4];
  if (lane == 63) ws[w] = incl;
  __syncthreads();
  int wpre = 0;
  for (int q = 0; q < w; q++) wpre += ws[q];
  int off = bpre[b] + wpre + excl;
  for (int q = 0; q < 4; q++) {
    int idx = base + q;
    if (idx < N) offsets[idx] = off;
    off += c[q];
  }
}

// cursor pre-seeded with offsets (d2d memcpy) -> single atomic, no offsets read
__global__ void fill_kernel(const int* __restrict__ src, const int* __restrict__ dst,
                            int* __restrict__ cursor, int2* __restrict__ edges, int E) {
  int e = blockIdx.x * 256 + threadIdx.x;
  if (e < E) {
    int d = dst[e];
    int pos = atomicAdd(&cursor[d], 1);
    edges[pos] = make_int2(src[e], d);
  }
}

// ---------------- MFMA per-edge scores -> ek = exp(leaky_relu(mlp)), fp16 ----------------
// Round-7 lesson: compiler collapsed the explicit 2-deep staging (VGPR 52 << the 128
// staging needs) -> ILP plan dead; occupancy tracked the launch_bounds waves arg
// (3 -> 38%). So get MLP from TLP instead: 8 waves/SIMD (VGPR cap 64 >= 52).
__launch_bounds__(256, 8)
__global__ void score_kernel(const _Float16* __restrict__ u_cat, const _Float16* __restrict__ v_cat,
                             const int2* __restrict__ edges,
                             const float* __restrict__ w2a, const float* __restrict__ w2b,
                             const float* __restrict__ b2a, const float* __restrict__ b2b,
                             _Float16* __restrict__ ek, int E) {
  __shared__ _Float16 sB[8 * 64 * 8];   // [t][lane][j] B-fragments of W2cat (block-diag)
  int tid = threadIdx.x, lane = tid & 63, w = tid >> 6;
  int col = lane & 15, kg = lane >> 4;
  for (int idx = tid; idx < 4096; idx += 256) {
    int t = idx >> 9, l = (idx >> 3) & 63, j = idx & 7;
    int bc = l & 15;
    int k = t * 32 + ((l >> 4) << 3) + j;
    float val = 0.f;
    if (bc < 4) { if (k < 128) val = w2a[k * 4 + bc]; }
    else if (bc < 8) { if (k >= 128) val = w2b[(k - 128) * 4 + (bc - 4)]; }
    sB[idx] = (_Float16)val;
  }
  __syncthreads();

  int ebase = blockIdx.x * 256 + w * 64;

  // fragment-layout gather pointers: lane (col,kg) serves edge (m*16+col), k-offset kg*8
  const _Float16* up[4];
  const _Float16* vp[4];
#pragma unroll
  for (int m = 0; m < 4; m++) {
    int em = ebase + m * 16 + col;
    int ec = em < E ? em : 0;          // clamp; epilogue guards stores
    int2 sd = edges[ec];
    up[m] = u_cat + (size_t)sd.x * 256 + kg * 8;
    vp[m] = v_cat + (size_t)sd.y * 256 + kg * 8;
  }

  f32x4v acc[4];
#pragma unroll
  for (int m = 0; m < 4; m++) acc[m] = (f32x4v){0.f, 0.f, 0.f, 0.f};

#pragma unroll
  for (int t = 0; t < 8; t++) {
    fh8 bf = *(const fh8*)(sB + ((t * 64 + lane) << 3));
#pragma unroll
    for (int m = 0; m < 4; m++) {
      fh8 uu = *(const fh8*)(up[m] + t * 32);
      fh8 vv = *(const fh8*)(vp[m] + t * 32);
      acc[m] = __builtin_amdgcn_mfma_f32_16x16x32_f16(relu8(uu + vv), bf, acc[m], 0, 0, 0);
    }
  }

  // C layout: col = lane&15 (head), row = kg*4 + q (edge within 16-tile)  [m89/m91]
  if (col < 8) {
    float b2v = (col < 4) ? b2a[col] : b2b[col - 4];
#pragma unroll
    for (int m = 0; m < 4; m++) {
#pragma unroll
      for (int q = 0; q < 4; q++) {
        int er = ebase + m * 16 + kg * 4 + q;
        if (er < E) {
          float x = acc[m][q] + b2v;
          x = x > 0.f ? x : 0.01f * x;
          ek[(size_t)er * 8 + col] = (_Float16)__expf(x);
        }
      }
    }
  }
}

// ---------------- softmax-normalize + aggregate: one wave per dst node, ONE pass ----------------
// 4-edge unroll: 4 independent src->h load chains + 4 ek loads in flight per iter
__launch_bounds__(256, 6)
__global__ void agg_kernel(const _Float16* __restrict__ ek, const int2* __restrict__ edges,
                           const int* __restrict__ offsets, const _Float16* __restrict__ h16,
                           float* __restrict__ out, int N) {
  int wid = blockIdx.x * 4 + (threadIdx.x >> 6);
  int lane = threadIdx.x & 63;
  if (wid >= N) return;
  int off0 = offsets[wid], off1 = offsets[wid + 1];
  int deg = off1 - off0;
  float* op = out + (size_t)wid * 512;
  if (deg == 0) {
#pragma unroll
    for (int k = 0; k < 4; k++) { op[k * 128 + lane] = 0.f; op[k * 128 + 64 + lane] = 0.f; }
    return;
  }
  float accO[8] = {0, 0, 0, 0, 0, 0, 0, 0};
  float ssum[8] = {0, 0, 0, 0, 0, 0, 0, 0};
  int last = off1 - 1;
  for (int jj = 0; jj < deg; jj += 4) {
    int i0 = off0 + jj;
    int i1 = min(i0 + 1, last), i2 = min(i0 + 2, last), i3 = min(i0 + 3, last);
    bool m1 = jj + 1 < deg, m2 = jj + 2 < deg, m3 = jj + 3 < deg;
    int s0 = edges[i0].x, s1 = edges[i1].x, s2 = edges[i2].x, s3 = edges[i3].x;
    fh8 e0 = *(const fh8*)(ek + (size_t)i0 * 8);
    fh8 e1 = *(const fh8*)(ek + (size_t)i1 * 8);
    fh8 e2 = *(const fh8*)(ek + (size_t)i2 * 8);
    fh8 e3 = *(const fh8*)(ek + (size_t)i3 * 8);
    float hv0 = (float)h16[(size_t)s0 * DH + lane];
    float hv1 = (float)h16[(size_t)s1 * DH + lane];
    float hv2 = (float)h16[(size_t)s2 * DH + lane];
    float hv3 = (float)h16[(size_t)s3 * DH + lane];
#pragma unroll
    for (int k = 0; k < 8; k++) {
      float e0v = (float)e0[k];
      float e1v = m1 ? (float)e1[k] : 0.f;
      float e2v = m2 ? (float)e2[k] : 0.f;
      float e3v = m3 ? (float)e3[k] : 0.f;
      accO[k] = fmaf(e0v, hv0, accO[k]);
      accO[k] = fmaf(e1v, hv1, accO[k]);
      accO[k] = fmaf(e2v, hv2, accO[k]);
      accO[k] = fmaf(e3v, hv3, accO[k]);
      ssum[k] += (e0v + e1v) + (e2v + e3v);
    }
  }
#pragma unroll
  for (int k = 0; k < 8; k++) {
    float rsv = 1.f / ssum[k];
    int colo = k < 4 ? k * 128 + lane : (k - 4) * 128 + 64 + lane;
    op[colo] = accO[k] * rsv;
  }
}

extern "C" void kernel_launch(void* const* d_in, const int* in_sizes, int n_in,
                              void* d_out, int out_size, void* d_ws, size_t ws_size,
                              hipStream_t stream) {
  const float* h      = (const float*)d_in[0];
  const float* pca    = (const float*)d_in[1];
  const float* pimg   = (const float*)d_in[2];
  const float* pca_w1 = (const float*)d_in[3];
  const float* pca_b1 = (const float*)d_in[4];
  const float* pca_w2 = (const float*)d_in[5];
  const float* pca_b2 = (const float*)d_in[6];
  const float* pi_w1  = (const float*)d_in[7];
  const float* pi_b1  = (const float*)d_in[8];
  const float* pi_w2  = (const float*)d_in[9];
  const float* pi_b2  = (const float*)d_in[10];
  const int*   src    = (const int*)d_in[11];
  const int*   dst    = (const int*)d_in[12];
  int N = in_sizes[0] / 64;
  int E = in_sizes[11];
  float* out = (float*)d_out;

  char* ws = (char*)d_ws;
  size_t o = 0;
  auto alloc = [&](size_t bytes) { void* p = ws + o; o += (bytes + 255) & ~(size_t)255; return p; };
  _Float16* u_cat = (_Float16*)alloc((size_t)N * 256 * 2);
  _Float16* v_cat = (_Float16*)alloc((size_t)N * 256 * 2);
  _Float16* h16   = (_Float16*)alloc((size_t)N * 64 * 2);
  int* counts  = (int*)alloc((size_t)N * 4);
  int* cursor  = (int*)alloc((size_t)N * 4);
  int* offsets = (int*)alloc((size_t)(N + 1) * 4);
  int* bsums   = (int*)alloc(1024 * 4);
  int* bpre    = (int*)alloc(1024 * 4);
  int2* edges  = (int2*)alloc((size_t)E * 8);
  _Float16* ekb = (_Float16*)alloc((size_t)E * 8 * 2);

  hipMemsetAsync(counts, 0, (size_t)N * 4, stream);

  uv_kernel<64, 32><<<(N + 31) / 32, 256, 0, stream>>>(pca, pca_w1, pca_b1, u_cat, v_cat, 0, N);
  uv_kernel<32, 32><<<(N + 31) / 32, 256, 0, stream>>>(pimg, pi_w1, pi_b1, u_cat, v_cat, 128, N);
  h16_kernel<<<((N * 64) / 4 + 255) / 256, 256, 0, stream>>>(h, h16, N * 64);
  count_kernel<<<(E + 255) / 256, 256, 0, stream>>>(dst, counts, E);
  int NB = (N + 1023) / 1024;
  scan1_kernel<<<NB, 256, 0, stream>>>(counts, bsums, N);
  scan2_kernel<<<1, 1024, 0, stream>>>(bsums, bpre, offsets, NB, N, E);
  scan3_kernel<<<NB, 256, 0, stream>>>(counts, bpre, offsets, N);
  hipMemcpyAsync(cursor, offsets, (size_t)N * 4, hipMemcpyDeviceToDevice, stream);
  fill_kernel<<<(E + 255) / 256, 256, 0, stream>>>(src, dst, cursor, edges, E);
  score_kernel<<<(E + 255) / 256, 256, 0, stream>>>(u_cat, v_cat, edges,
                                                    pca_w2, pi_w2, pca_b2, pi_b2, ekb, E);
  agg_kernel<<<(N + 3) / 4, 256, 0, stream>>>(ekb, edges, offsets, h16, out, N);
}

// Round 9
// 290.119 us; speedup vs baseline: 1.6573x; 1.1136x over previous
//
#include <hip/hip_runtime.h>
#include <hip/hip_fp16.h>

constexpr int HID = 128;
constexpr int DH  = 64;

typedef _Float16 f16x2 __attribute__((ext_vector_type(2)));
typedef _Float16 fh8   __attribute__((ext_vector_type(8)));   // 4 VGPRs, MFMA A/B frag
typedef float    f32x4v __attribute__((ext_vector_type(4)));  // MFMA C/D frag

__device__ __forceinline__ fh8 relu8(fh8 x) {
  fh8 z = {0, 0, 0, 0, 0, 0, 0, 0};
#if __has_builtin(__builtin_elementwise_max)
  return __builtin_elementwise_max(x, z);
#else
  fh8 r;
#pragma unroll
  for (int i = 0; i < 8; i++) r[i] = x[i] > z[i] ? x[i] : z[i];
  return r;
#endif
}

// ---------------- W1 B-fragment table setup (runs once, scattered reads) ----------------
// fragTab[rel][g][s][l][j] = W1_rel[krow][jout], k = s*32+(l>>4)*8+j, jout=(g&7)*16+(l&15)
// g<8: u part (krow=k); g>=8: v part (krow=F+k). Zero-padded where k>=F.
__global__ void frag_setup_kernel(const float* __restrict__ w1a, const float* __restrict__ w1b,
                                  _Float16* __restrict__ fragTab) {
  int flat = blockIdx.x * 256 + threadIdx.x;
  if (flat >= 32768) return;
  int rel = flat >> 14;
  int r2 = flat & 16383;
  int g = r2 >> 10, s = (r2 >> 9) & 1, l = (r2 >> 3) & 63, j = r2 & 7;
  int bc = l & 15, bkg = l >> 4;
  int k = s * 32 + bkg * 8 + j;
  int F = rel ? 32 : 64;
  const float* w1 = rel ? w1b : w1a;
  float val = 0.f;
  if (k < F) {
    int jout = (g & 7) * 16 + bc;
    int krow = (g < 8) ? k : (F + k);
    val = w1[krow * HID + jout];
  }
  fragTab[flat] = (_Float16)val;
}

// ---------------- uv precompute via MFMA: [u|v] = feat @ [W1top|W1bot], v += b1 ----------
// block = 64 nodes x (u 128 + v 128 cols) for relation blockIdx.y; 4 waves x 16 nodes.
__launch_bounds__(256)
__global__ void uv_mfma_kernel(const float* __restrict__ pca, const float* __restrict__ pimg,
                               const float* __restrict__ b1a, const float* __restrict__ b1b,
                               const _Float16* __restrict__ fragTab,
                               _Float16* __restrict__ u_cat, _Float16* __restrict__ v_cat, int N) {
  __shared__ _Float16 sB[16384];   // [g(16)][s(2)][l(64)][j(8)]
  int rel = blockIdx.y;
  const float* feat = rel ? pimg : pca;
  const float* b1   = rel ? b1b : b1a;
  int F  = rel ? 32 : 64;
  int KS = rel ? 1 : 2;
  int tid = threadIdx.x;
  {  // linear coalesced copy of this relation's frag table
    const fh8* srcp = (const fh8*)(fragTab + rel * 16384);
    fh8* dstp = (fh8*)sB;
    for (int i = tid; i < 2048; i += 256) dstp[i] = srcp[i];
  }
  __syncthreads();
  int lane = tid & 63, w = tid >> 6;
  int r = lane & 15, kg = lane >> 4;
  int node = blockIdx.x * 64 + w * 16 + r;
  int nclamp = node < N ? node : N - 1;
  fh8 a[2];
#pragma unroll
  for (int s = 0; s < 2; s++) {
    if (s < KS) {
      const float* fp = feat + (size_t)nclamp * F + s * 32 + kg * 8;
      float4 f0 = *(const float4*)fp;
      float4 f1 = *(const float4*)(fp + 4);
      fh8 t;
      t[0] = (_Float16)f0.x; t[1] = (_Float16)f0.y; t[2] = (_Float16)f0.z; t[3] = (_Float16)f0.w;
      t[4] = (_Float16)f1.x; t[5] = (_Float16)f1.y; t[6] = (_Float16)f1.z; t[7] = (_Float16)f1.w;
      a[s] = t;
    }
  }
  int onode0 = blockIdx.x * 64 + w * 16 + kg * 4;   // C rows: kg*4+q
  int c = lane & 15;
#pragma unroll
  for (int g = 0; g < 16; g++) {
    f32x4v acc = {0.f, 0.f, 0.f, 0.f};
    acc = __builtin_amdgcn_mfma_f32_16x16x32_f16(a[0], ((const fh8*)sB)[(g * 2 + 0) * 64 + lane], acc, 0, 0, 0);
    if (KS == 2)
      acc = __builtin_amdgcn_mfma_f32_16x16x32_f16(a[1], ((const fh8*)sB)[(g * 2 + 1) * 64 + lane], acc, 0, 0, 0);
    bool isv = g >= 8;
    int jout = (g & 7) * 16 + c;
    float bias = isv ? b1[jout] : 0.f;
    _Float16* outp = isv ? v_cat : u_cat;
    size_t colix = (size_t)rel * 128 + jout;
#pragma unroll
    for (int q = 0; q < 4; q++) {
      int on = onode0 + q;
      if (on < N) outp[(size_t)on * 256 + colix] = (_Float16)(acc[q] + bias);
    }
  }
}

// ---------------- merged: degree count + h -> fp16 convert ----------------
__global__ void count_h16_kernel(const int* __restrict__ dst, int* __restrict__ counts, int E,
                                 const float* __restrict__ h, _Float16* __restrict__ h16, int total) {
  int i = blockIdx.x * 256 + threadIdx.x;
  if (i < E) atomicAdd(&counts[dst[i]], 1);
  int base = i * 8;
  if (base + 7 < total) {
    float4 f0 = *(const float4*)(h + base);
    float4 f1 = *(const float4*)(h + base + 4);
    fh8 t;
    t[0] = (_Float16)f0.x; t[1] = (_Float16)f0.y; t[2] = (_Float16)f0.z; t[3] = (_Float16)f0.w;
    t[4] = (_Float16)f1.x; t[5] = (_Float16)f1.y; t[6] = (_Float16)f1.z; t[7] = (_Float16)f1.w;
    *(fh8*)(h16 + base) = t;
  }
}

// ---------------- CSR scans ----------------
__launch_bounds__(256)
__global__ void scan1_kernel(const int* __restrict__ counts, int* __restrict__ bsums, int N) {
  int b = blockIdx.x, tid = threadIdx.x;
  int base = b * 1024 + tid * 4;
  int s = 0;
  if (base + 3 < N) {
    int4 v = *(const int4*)(counts + base);
    s = v.x + v.y + v.z + v.w;
  } else {
    for (int q = 0; q < 4; q++) { int idx = base + q; if (idx < N) s += counts[idx]; }
  }
#pragma unroll
  for (int o = 32; o >= 1; o >>= 1) s += __shfl_xor(s, o);
  __shared__ int ws[4];
  if ((tid & 63) == 0) ws[tid >> 6] = s;
  __syncthreads();
  if (tid == 0) bsums[b] = ws[0] + ws[1] + ws[2] + ws[3];
}

__launch_bounds__(1024)
__global__ void scan2_kernel(const int* __restrict__ bsums, int* __restrict__ bpre,
                             int* __restrict__ offsets, int NB, int N, int E) {
  int tid = threadIdx.x, lane = tid & 63, w = tid >> 6;
  int v = (tid < NB) ? bsums[tid] : 0;
  int incl = v;
#pragma unroll
  for (int o = 1; o < 64; o <<= 1) { int t = __shfl_up(incl, o); if (lane >= o) incl += t; }
  __shared__ int ws[16];
  if (lane == 63) ws[w] = incl;
  __syncthreads();
  int wpre = 0;
  for (int q = 0; q < w; q++) wpre += ws[q];
  if (tid < NB) bpre[tid] = wpre + incl - v;
  if (tid == 0) offsets[N] = E;
}

__launch_bounds__(256)
__global__ void scan3_kernel(const int* __restrict__ counts, const int* __restrict__ bpre,
                             int* __restrict__ offsets, int N) {
  int b = blockIdx.x, tid = threadIdx.x, lane = tid & 63, w = tid >> 6;
  int base = b * 1024 + tid * 4;
  int c[4] = {0, 0, 0, 0};
  if (base + 3 < N) {
    int4 v = *(const int4*)(counts + base);
    c[0] = v.x; c[1] = v.y; c[2] = v.z; c[3] = v.w;
  } else {
    for (int q = 0; q < 4; q++) { int idx = base + q; if (idx < N) c[q] = counts[idx]; }
  }
  int s = c[0] + c[1] + c[2] + c[3];
  int incl = s;
#pragma unroll
  for (int o = 1; o < 64; o <<= 1) { int t = __shfl_up(incl, o); if (lane >= o) incl += t; }
  int excl = incl - s;
  __shared__ int ws[4];
  if (lane == 63) ws[w] = incl;
  __syncthreads();
  int wpre = 0;
  for (int q = 0; q < w; q++) wpre += ws[q];
  int off = bpre[b] + wpre + excl;
  for (int q = 0; q < 4; q++) {
    int idx = base + q;
    if (idx < N) offsets[idx] = off;
    off += c[q];
  }
}

// cursor pre-seeded with offsets (d2d memcpy) -> single atomic, no offsets read
__global__ void fill_kernel(const int* __restrict__ src, const int* __restrict__ dst,
                            int* __restrict__ cursor, int2* __restrict__ edges, int E) {
  int e = blockIdx.x * 256 + threadIdx.x;
  if (e < E) {
    int d = dst[e];
    int pos = atomicAdd(&cursor[d], 1);
    edges[pos] = make_int2(src[e], d);
  }
}

// ---------------- MFMA per-edge scores -> ek = exp(leaky_relu(mlp)), fp16 ----------------
// At ~92% of the measured random-gather fabric wall (206MB L2-miss @ ~2.6 TB/s) — unchanged.
__launch_bounds__(256, 8)
__global__ void score_kernel(const _Float16* __restrict__ u_cat, const _Float16* __restrict__ v_cat,
                             const int2* __restrict__ edges,
                             const float* __restrict__ w2a, const float* __restrict__ w2b,
                             const float* __restrict__ b2a, const float* __restrict__ b2b,
                             _Float16* __restrict__ ek, int E) {
  __shared__ _Float16 sB[8 * 64 * 8];   // [t][lane][j] B-fragments of W2cat (block-diag)
  int tid = threadIdx.x, lane = tid & 63, w = tid >> 6;
  int col = lane & 15, kg = lane >> 4;
  for (int idx = tid; idx < 4096; idx += 256) {
    int t = idx >> 9, l = (idx >> 3) & 63, j = idx & 7;
    int bc = l & 15;
    int k = t * 32 + ((l >> 4) << 3) + j;
    float val = 0.f;
    if (bc < 4) { if (k < 128) val = w2a[k * 4 + bc]; }
    else if (bc < 8) { if (k >= 128) val = w2b[(k - 128) * 4 + (bc - 4)]; }
    sB[idx] = (_Float16)val;
  }
  __syncthreads();

  int ebase = blockIdx.x * 256 + w * 64;
  const _Float16* up[4];
  const _Float16* vp[4];
#pragma unroll
  for (int m = 0; m < 4; m++) {
    int em = ebase + m * 16 + col;
    int ec = em < E ? em : 0;          // clamp; epilogue guards stores
    int2 sd = edges[ec];
    up[m] = u_cat + (size_t)sd.x * 256 + kg * 8;
    vp[m] = v_cat + (size_t)sd.y * 256 + kg * 8;
  }

  f32x4v acc[4];
#pragma unroll
  for (int m = 0; m < 4; m++) acc[m] = (f32x4v){0.f, 0.f, 0.f, 0.f};

#pragma unroll
  for (int t = 0; t < 8; t++) {
    fh8 bf = *(const fh8*)(sB + ((t * 64 + lane) << 3));
#pragma unroll
    for (int m = 0; m < 4; m++) {
      fh8 uu = *(const fh8*)(up[m] + t * 32);
      fh8 vv = *(const fh8*)(vp[m] + t * 32);
      acc[m] = __builtin_amdgcn_mfma_f32_16x16x32_f16(relu8(uu + vv), bf, acc[m], 0, 0, 0);
    }
  }

  if (col < 8) {
    float b2v = (col < 4) ? b2a[col] : b2b[col - 4];
#pragma unroll
    for (int m = 0; m < 4; m++) {
#pragma unroll
      for (int q = 0; q < 4; q++) {
        int er = ebase + m * 16 + kg * 4 + q;
        if (er < E) {
          float x = acc[m][q] + b2v;
          x = x > 0.f ? x : 0.01f * x;
          ek[(size_t)er * 8 + col] = (_Float16)__expf(x);
        }
      }
    }
  }
}

// ---------------- softmax-normalize + aggregate: one wave per dst node, ONE pass ----------------
__launch_bounds__(256, 8)
__global__ void agg_kernel(const _Float16* __restrict__ ek, const int2* __restrict__ edges,
                           const int* __restrict__ offsets, const _Float16* __restrict__ h16,
                           float* __restrict__ out, int N) {
  int wid = blockIdx.x * 4 + (threadIdx.x >> 6);
  int lane = threadIdx.x & 63;
  if (wid >= N) return;
  int off0 = offsets[wid], off1 = offsets[wid + 1];
  int deg = off1 - off0;
  float* op = out + (size_t)wid * 512;
  if (deg == 0) {
#pragma unroll
    for (int k = 0; k < 4; k++) { op[k * 128 + lane] = 0.f; op[k * 128 + 64 + lane] = 0.f; }
    return;
  }
  float accO[8] = {0, 0, 0, 0, 0, 0, 0, 0};
  float ssum[8] = {0, 0, 0, 0, 0, 0, 0, 0};
  int last = off1 - 1;
  for (int jj = 0; jj < deg; jj += 4) {
    int i0 = off0 + jj;
    int i1 = min(i0 + 1, last), i2 = min(i0 + 2, last), i3 = min(i0 + 3, last);
    bool m1 = jj + 1 < deg, m2 = jj + 2 < deg, m3 = jj + 3 < deg;
    int s0 = edges[i0].x, s1 = edges[i1].x, s2 = edges[i2].x, s3 = edges[i3].x;
    fh8 e0 = *(const fh8*)(ek + (size_t)i0 * 8);
    fh8 e1 = *(const fh8*)(ek + (size_t)i1 * 8);
    fh8 e2 = *(const fh8*)(ek + (size_t)i2 * 8);
    fh8 e3 = *(const fh8*)(ek + (size_t)i3 * 8);
    float hv0 = (float)h16[(size_t)s0 * DH + lane];
    float hv1 = (float)h16[(size_t)s1 * DH + lane];
    float hv2 = (float)h16[(size_t)s2 * DH + lane];
    float hv3 = (float)h16[(size_t)s3 * DH + lane];
#pragma unroll
    for (int k = 0; k < 8; k++) {
      float e0v = (float)e0[k];
      float e1v = m1 ? (float)e1[k] : 0.f;
      float e2v = m2 ? (float)e2[k] : 0.f;
      float e3v = m3 ? (float)e3[k] : 0.f;
      accO[k] = fmaf(e0v, hv0, accO[k]);
      accO[k] = fmaf(e1v, hv1, accO[k]);
      accO[k] = fmaf(e2v, hv2, accO[k]);
      accO[k] = fmaf(e3v, hv3, accO[k]);
      ssum[k] += (e0v + e1v) + (e2v + e3v);
    }
  }
#pragma unroll
  for (int k = 0; k < 8; k++) {
    float rsv = 1.f / ssum[k];
    int colo = k < 4 ? k * 128 + lane : (k - 4) * 128 + 64 + lane;
    op[colo] = accO[k] * rsv;
  }
}

extern "C" void kernel_launch(void* const* d_in, const int* in_sizes, int n_in,
                              void* d_out, int out_size, void* d_ws, size_t ws_size,
                              hipStream_t stream) {
  const float* h      = (const float*)d_in[0];
  const float* pca    = (const float*)d_in[1];
  const float* pimg   = (const float*)d_in[2];
  const float* pca_w1 = (const float*)d_in[3];
  const float* pca_b1 = (const float*)d_in[4];
  const float* pca_w2 = (const float*)d_in[5];
  const float* pca_b2 = (const float*)d_in[6];
  const float* pi_w1  = (const float*)d_in[7];
  const float* pi_b1  = (const float*)d_in[8];
  const float* pi_w2  = (const float*)d_in[9];
  const float* pi_b2  = (const float*)d_in[10];
  const int*   src    = (const int*)d_in[11];
  const int*   dst    = (const int*)d_in[12];
  int N = in_sizes[0] / 64;
  int E = in_sizes[11];
  float* out = (float*)d_out;

  char* ws = (char*)d_ws;
  size_t o = 0;
  auto alloc = [&](size_t bytes) { void* p = ws + o; o += (bytes + 255) & ~(size_t)255; return p; };
  _Float16* u_cat  = (_Float16*)alloc((size_t)N * 256 * 2);
  _Float16* v_cat  = (_Float16*)alloc((size_t)N * 256 * 2);
  _Float16* h16    = (_Float16*)alloc((size_t)N * 64 * 2);
  _Float16* fragTab = (_Float16*)alloc(32768 * 2);
  int* counts  = (int*)alloc((size_t)N * 4);
  int* cursor  = (int*)alloc((size_t)N * 4);
  int* offsets = (int*)alloc((size_t)(N + 1) * 4);
  int* bsums   = (int*)alloc(1024 * 4);
  int* bpre    = (int*)alloc(1024 * 4);
  int2* edges  = (int2*)alloc((size_t)E * 8);
  _Float16* ekb = (_Float16*)alloc((size_t)E * 8 * 2);

  hipMemsetAsync(counts, 0, (size_t)N * 4, stream);

  frag_setup_kernel<<<128, 256, 0, stream>>>(pca_w1, pi_w1, fragTab);
  count_h16_kernel<<<(E + 255) / 256, 256, 0, stream>>>(dst, counts, E, h, h16, N * 64);
  dim3 uvgrid((N + 63) / 64, 2);
  uv_mfma_kernel<<<uvgrid, 256, 0, stream>>>(pca, pimg, pca_b1, pi_b1, fragTab, u_cat, v_cat, N);
  int NB = (N + 1023) / 1024;
  scan1_kernel<<<NB, 256, 0, stream>>>(counts, bsums, N);
  scan2_kernel<<<1, 1024, 0, stream>>>(bsums, bpre, offsets, NB, N, E);
  scan3_kernel<<<NB, 256, 0, stream>>>(counts, bpre, offsets, N);
  hipMemcpyAsync(cursor, offsets, (size_t)N * 4, hipMemcpyDeviceToDevice, stream);
  fill_kernel<<<(E + 255) / 256, 256, 0, stream>>>(src, dst, cursor, edges, E);
  score_kernel<<<(E + 255) / 256, 256, 0, stream>>>(u_cat, v_cat, edges,
                                                    pca_w2, pi_w2, pca_b2, pi_b2, ekb, E);
  agg_kernel<<<(N + 3) / 4, 256, 0, stream>>>(ekb, edges, offsets, h16, out, N);
}